// Round 17
// baseline (297.956 us; speedup 1.0000x reference)
//
#include <hip/hip_runtime.h>
#include <hip/hip_bf16.h>
#include <math.h>

#define BATCH 8
#define SQL 4096
#define SKL 4096
#define DIM 256
#define KVB 64
#define NIT (SKL / KVB)

typedef __attribute__((ext_vector_type(8))) short short8;
typedef __attribute__((ext_vector_type(4))) float f32x4;
typedef __attribute__((ext_vector_type(4))) float floatx4;

typedef __attribute__((address_space(3))) unsigned int lds_uint;
typedef __attribute__((address_space(1))) unsigned int glob_uint;

__device__ __forceinline__ void gl_lds16(const void* g, void* l) {
  __builtin_amdgcn_global_load_lds((const glob_uint*)g, (lds_uint*)l, 16, 0, 0);
}

__device__ __forceinline__ short f2bf(float f) {
  union { float f; unsigned u; } x; x.f = f;
  unsigned r = x.u + 0x7fffu + ((x.u >> 16) & 1u);
  return (short)(r >> 16);
}

// Kt rows 512B / Vt rows 128B: slot ^= row&7 (2-way residue, ~free). Pl padded.
__device__ __forceinline__ int swz(int row) { return (row & 7) << 4; }

// max-reduce across a 16-lane DPP row, pure VALU, bit-exact (R12-proven)
__device__ __forceinline__ float dpp_max16(float v) {
  float t;
  t = __int_as_float(__builtin_amdgcn_mov_dpp(__float_as_int(v), 0xB1, 0xF, 0xF, true));  // quad_perm xor1
  v = fmaxf(v, t);
  t = __int_as_float(__builtin_amdgcn_mov_dpp(__float_as_int(v), 0x4E, 0xF, 0xF, true));  // quad_perm xor2
  v = fmaxf(v, t);
  t = __int_as_float(__builtin_amdgcn_mov_dpp(__float_as_int(v), 0x124, 0xF, 0xF, true)); // row_ror:4
  v = fmaxf(v, t);
  t = __int_as_float(__builtin_amdgcn_mov_dpp(__float_as_int(v), 0x128, 0xF, 0xF, true)); // row_ror:8
  v = fmaxf(v, t);
  return v;
}

// ---------- merged projections: one kernel for Q, K, V^T ----------
// grid = 3 x 512 blocks; mtype = blockIdx>>9 selects {Q,K,V}. W converted
// fp32->bf16 in-register (bitwise = old wcvt path); W is L2-resident.
__global__ __launch_bounds__(256, 2) void proj_all_kernel(
    const float* __restrict__ query, const float* __restrict__ keys,
    const float* __restrict__ values,
    const float* __restrict__ Wq, const float* __restrict__ bq,
    const float* __restrict__ Wk, const float* __restrict__ bk,
    const float* __restrict__ Wv, const float* __restrict__ bv,
    short* __restrict__ Qb, short* __restrict__ Kb, short* __restrict__ VtT)
{
  __shared__ short tile[32][264];

  const int mtype = blockIdx.x >> 9;            // 0=Q, 1=K, 2=V^T
  const int mb    = blockIdx.x & 511;
  const int lane = threadIdx.x & 63;
  const int wave = threadIdx.x >> 6;
  const int lr = lane & 15, hi = lane >> 4;
  const int n0 = wave * 64;

  const float* X  = (mtype == 0) ? query : ((mtype == 1) ? keys : values);
  const float* W  = (mtype == 0) ? Wq    : ((mtype == 1) ? Wk   : Wv);
  const float* bb = (mtype == 0) ? bq    : ((mtype == 1) ? bk   : bv);

  // W-resident fragments, converted in-register (bitwise = wcvt+load)
  short8 wf[8][4];
  #pragma unroll
  for (int kk = 0; kk < 8; ++kk)
    #pragma unroll
    for (int nb = 0; nb < 4; ++nb) {
      const float* wrow = W + (size_t)(n0 + nb*16 + lr) * DIM + kk*32 + hi*8;
      floatx4 wa = *(const floatx4*)(wrow);
      floatx4 wb2 = *(const floatx4*)(wrow + 4);
      short8 w;
      #pragma unroll
      for (int j = 0; j < 4; ++j) { w[j] = f2bf(wa[j]); w[j+4] = f2bf(wb2[j]); }
      wf[kk][nb] = w;
    }

  float bv4[4];
  #pragma unroll
  for (int nb = 0; nb < 4; ++nb) bv4[nb] = bb[n0 + nb*16 + lr];

  if (mtype < 2) {
    // ---- Q/K path: 64 m-rows, row-major bf16 out ----
    short* out = (mtype == 0) ? Qb : Kb;
    const int m0 = mb * 64;
    #pragma unroll
    for (int ms = 0; ms < 4; ++ms) {
      const float* xrow = X + (size_t)(m0 + ms*16 + lr) * DIM;
      floatx4 xv0[8], xv1[8];
      #pragma unroll
      for (int kk = 0; kk < 8; ++kk) {
        xv0[kk] = *(const floatx4*)(xrow + kk*32 + hi*8);
        xv1[kk] = *(const floatx4*)(xrow + kk*32 + hi*8 + 4);
      }
      f32x4 acc[4] = {(f32x4)0.f,(f32x4)0.f,(f32x4)0.f,(f32x4)0.f};
      #pragma unroll
      for (int kk = 0; kk < 8; ++kk) {
        short8 a;
        #pragma unroll
        for (int j = 0; j < 4; ++j) { a[j] = f2bf(xv0[kk][j]); a[j+4] = f2bf(xv1[kk][j]); }
        #pragma unroll
        for (int nb = 0; nb < 4; ++nb)
          acc[nb] = __builtin_amdgcn_mfma_f32_16x16x32_bf16(a, wf[kk][nb], acc[nb], 0, 0, 0);
      }
      #pragma unroll
      for (int nb = 0; nb < 4; ++nb)
        #pragma unroll
        for (int r = 0; r < 4; ++r)
          out[(size_t)(m0 + ms*16 + hi*4 + r) * DIM + n0 + nb*16 + lr] = f2bf(acc[nb][r] + bv4[nb]);
    }
  } else {
    // ---- V path: 64 rows = 2 x 32-row transpose chunks -> outT[b][d][k] ----
    #pragma unroll
    for (int ms = 0; ms < 2; ++ms) {
      const int mbase = mb * 64 + ms * 32;

      f32x4 acc0[4] = {(f32x4)0.f,(f32x4)0.f,(f32x4)0.f,(f32x4)0.f};
      f32x4 acc1[4] = {(f32x4)0.f,(f32x4)0.f,(f32x4)0.f,(f32x4)0.f};
      const float* xr0 = X + (size_t)(mbase + lr) * DIM;
      const float* xr1 = X + (size_t)(mbase + 16 + lr) * DIM;

      #pragma unroll
      for (int kk = 0; kk < 8; ++kk) {
        const int k8 = kk * 32 + hi * 8;
        floatx4 xa = *(const floatx4*)(xr0 + k8);
        floatx4 xb2 = *(const floatx4*)(xr0 + k8 + 4);
        floatx4 ya = *(const floatx4*)(xr1 + k8);
        floatx4 yb2 = *(const floatx4*)(xr1 + k8 + 4);
        short8 a0, a1;
        #pragma unroll
        for (int j = 0; j < 4; ++j) {
          a0[j] = f2bf(xa[j]); a0[j+4] = f2bf(xb2[j]);
          a1[j] = f2bf(ya[j]); a1[j+4] = f2bf(yb2[j]);
        }
        #pragma unroll
        for (int nb = 0; nb < 4; ++nb) {
          acc0[nb] = __builtin_amdgcn_mfma_f32_16x16x32_bf16(a0, wf[kk][nb], acc0[nb], 0, 0, 0);
          acc1[nb] = __builtin_amdgcn_mfma_f32_16x16x32_bf16(a1, wf[kk][nb], acc1[nb], 0, 0, 0);
        }
      }
      #pragma unroll
      for (int nb = 0; nb < 4; ++nb) {
        const int n = n0 + nb*16 + lr;
        #pragma unroll
        for (int r = 0; r < 4; ++r) {
          tile[hi*4 + r][n]      = f2bf(acc0[nb][r] + bv4[nb]);
          tile[16 + hi*4 + r][n] = f2bf(acc1[nb][r] + bv4[nb]);
        }
      }
      __syncthreads();
      const int t = threadIdx.x;
      short8 v0, v1, v2, v3;
      #pragma unroll
      for (int k = 0; k < 8; ++k) {
        v0[k] = tile[k][t]; v1[k] = tile[k+8][t];
        v2[k] = tile[k+16][t]; v3[k] = tile[k+24][t];
      }
      const int b  = mbase >> 12;
      const int k0 = mbase & (SKL - 1);
      short* p = VtT + (size_t)b * DIM * SKL + (size_t)t * SKL + k0;
      *(short8*)(p)      = v0;
      *(short8*)(p + 8)  = v1;
      *(short8*)(p + 16) = v2;
      *(short8*)(p + 24) = v3;
      __syncthreads();   // protect tile before next ms overwrites it
    }
  }
}

// ---------- flash attention: R12 VERBATIM (proven 229 us, absmax 0.05859375) ----------
__global__ __launch_bounds__(512, 1) void attn_kernel(
    const short* __restrict__ Qb, const short* __restrict__ Kb,
    const short* __restrict__ VtG, float* __restrict__ out)
{
  __shared__ alignas(16) short Kt[2][64][256];   // 64 KB, 512B rows, XOR swz
  __shared__ alignas(16) short Vt[2][256][64];   // 64 KB, 128B rows, XOR swz
  __shared__ alignas(16) short Pl[8][16][72];    // 18 KB, 144B rows (padded, no XOR)

  const int tid  = threadIdx.x;
  const int lane = tid & 63;
  const int wave = tid >> 6;                     // 0..7
  const int lr = lane & 15, hi = lane >> 4;

  const int b     = blockIdx.x & 7;     // batch -> XCD pinning (grid=256)
  const int qtile = blockIdx.x >> 3;
  const int q0w   = qtile * 128 + wave * 16;

  const short* Qp = Qb  + ((size_t)b * SQL + q0w) * DIM;
  const short* Kp = Kb  + (size_t)b * SKL * DIM;
  const short* Vp = VtG + (size_t)b * DIM * SKL;

  short8 qf[8];
  #pragma unroll
  for (int kk = 0; kk < 8; ++kk)
    qf[kk] = *(const short8*)(Qp + (size_t)lr * DIM + kk*32 + hi*8);

  f32x4 o[16];
  #pragma unroll
  for (int i = 0; i < 16; ++i) o[i] = (f32x4)0.f;
  float mr[4]   = {-3.0e38f,-3.0e38f,-3.0e38f,-3.0e38f};
  float lacc[4] = {0.f,0.f,0.f,0.f};

  auto stage = [&](int buf, int kv) {
    #pragma unroll
    for (int i = 0; i < 4; ++i) {              // K: 64 rows x 512B
      const int row0 = wave*8 + i*2;
      const int row  = row0 + (lane >> 5);
      const int colb = ((lane & 31) * 16) ^ swz(row);
      gl_lds16((const char*)(Kp + (size_t)(kv + row) * DIM) + colb, (void*)&Kt[buf][row0][0]);
    }
    #pragma unroll
    for (int i = 0; i < 4; ++i) {              // V^T: 256 rows x 128B
      const int d0 = wave*32 + i*8;
      const int d  = d0 + (lane >> 3);
      const int colb = ((lane & 7) * 16) ^ swz(d);
      gl_lds16((const char*)(Vp + (size_t)d * SKL + kv) + colb, (void*)&Vt[buf][d0][0]);
    }
  };

  stage(0, 0);
  __syncthreads();
  int cur = 0;

  const char* plw = (const char*)&Pl[wave][0][0];

  for (int it = 0; it < NIT; ++it) {
    if (it + 1 < NIT) stage(cur ^ 1, (it + 1) * KVB);

    // ---- QK^T: S[16q][64k] ----
    const char* ktb = (const char*)&Kt[cur][0][0];
    f32x4 s[4];
    #pragma unroll
    for (int ks = 0; ks < 4; ++ks) s[ks] = (f32x4)0.f;
    __builtin_amdgcn_s_setprio(1);
    #pragma unroll
    for (int kk = 0; kk < 8; ++kk) {
      #pragma unroll
      for (int ks = 0; ks < 4; ++ks) {
        const int row = ks*16 + lr;
        short8 kf = *(const short8*)(ktb + row*512 + (((kk*64) + hi*16) ^ swz(row)));
        s[ks] = __builtin_amdgcn_mfma_f32_16x16x32_bf16(qf[kk], kf, s[ks], 0, 0, 0);
      }
    }
    __builtin_amdgcn_s_setprio(0);

    // ---- EXACT online softmax (row = hi*4+r, col = ks*16+lr), DPP max-reduce ----
    #pragma unroll
    for (int r = 0; r < 4; ++r) {
      float mx = dpp_max16(fmaxf(fmaxf(s[0][r], s[1][r]), fmaxf(s[2][r], s[3][r])));
      if (mx > mr[r]) {                        // bit-exact skip of sc==1.0 rescale
        const float sc = __expf(mr[r] - mx);   // first iter: exp(-inf)=0
        mr[r] = mx;
        lacc[r] *= sc;
        #pragma unroll
        for (int dt = 0; dt < 16; ++dt) o[dt][r] *= sc;
      }
      const int row = hi*4 + r;
      #pragma unroll
      for (int ks = 0; ks < 4; ++ks) {
        const float p = __expf(s[ks][r] - mr[r]);   // <= 1
        lacc[r] += p;
        *(short*)(plw + row*144 + 2*(ks*16 + lr)) = f2bf(p);
      }
    }

    // ---- PV: O[16q][256d] += P[16q][64k] . V[64k][256d] ----
    const char* vtb = (const char*)&Vt[cur][0][0];
    short8 pa[2];
    #pragma unroll
    for (int kh = 0; kh < 2; ++kh)
      pa[kh] = *(const short8*)(plw + lr*144 + kh*64 + hi*16);
    __builtin_amdgcn_s_setprio(1);
    #pragma unroll
    for (int dt = 0; dt < 16; ++dt) {
      #pragma unroll
      for (int kh = 0; kh < 2; ++kh) {
        const int d = dt*16 + lr;
        short8 vf = *(const short8*)(vtb + d*128 + ((kh*64 + hi*16) ^ swz(d)));
        o[dt] = __builtin_amdgcn_mfma_f32_16x16x32_bf16(pa[kh], vf, o[dt], 0, 0, 0);
      }
    }
    __builtin_amdgcn_s_setprio(0);

    __syncthreads();
    cur ^= 1;
  }

  // ---- epilogue: one cross-lane reduce of l, normalize, store ----
  float lsum[4];
  #pragma unroll
  for (int r = 0; r < 4; ++r) lsum[r] = lacc[r];
  #pragma unroll
  for (int off = 8; off >= 1; off >>= 1)
    #pragma unroll
    for (int r = 0; r < 4; ++r)
      lsum[r] += __shfl_xor(lsum[r], off, 64);

  float* op = out + ((size_t)b * SQL + q0w) * DIM;
  #pragma unroll
  for (int r = 0; r < 4; ++r) {
    const float inv = 1.0f / lsum[r];
    #pragma unroll
    for (int dt = 0; dt < 16; ++dt)
      op[(size_t)(hi*4 + r) * DIM + dt*16 + lr] = o[dt][r] * inv;
  }
}

extern "C" void kernel_launch(void* const* d_in, const int* in_sizes, int n_in,
                              void* d_out, int out_size, void* d_ws, size_t ws_size,
                              hipStream_t stream) {
  const float* query  = (const float*)d_in[0];
  const float* keys   = (const float*)d_in[1];
  const float* values = (const float*)d_in[2];
  const float* Wq = (const float*)d_in[3];
  const float* bq = (const float*)d_in[4];
  const float* Wk = (const float*)d_in[5];
  const float* bk = (const float*)d_in[6];
  const float* Wv = (const float*)d_in[7];
  const float* bv = (const float*)d_in[8];
  float* out = (float*)d_out;

  const size_t elems = (size_t)BATCH * SQL * DIM;
  short* Qb  = (short*)d_ws;
  short* Kb  = Qb + elems;
  short* VtT = Kb + elems;

  dim3 blk(256, 1, 1);
  dim3 blk512(512, 1, 1);
  // one merged projection launch: 3 x 512 blocks (Q, K, V^T)
  proj_all_kernel<<<dim3(3*512, 1, 1), blk, 0, stream>>>(
      query, keys, values, Wq, bq, Wk, bk, Wv, bv, Qb, Kb, VtT);
  attn_kernel <<<dim3(BATCH*SQL/128, 1, 1), blk512, 0, stream>>>(Qb, Kb, VtT, out);
}

// Round 18
// 292.668 us; speedup vs baseline: 1.0181x; 1.0181x over previous
//
#include <hip/hip_runtime.h>
#include <hip/hip_bf16.h>
#include <math.h>

#define BATCH 8
#define SQL 4096
#define SKL 4096
#define DIM 256
#define KVB 64
#define NIT (SKL / KVB)

typedef __attribute__((ext_vector_type(8))) short short8;
typedef __attribute__((ext_vector_type(4))) float f32x4;
typedef __attribute__((ext_vector_type(4))) float floatx4;

typedef __attribute__((address_space(3))) unsigned int lds_uint;
typedef __attribute__((address_space(1))) unsigned int glob_uint;

__device__ __forceinline__ void gl_lds16(const void* g, void* l) {
  __builtin_amdgcn_global_load_lds((const glob_uint*)g, (lds_uint*)l, 16, 0, 0);
}

__device__ __forceinline__ short f2bf(float f) {
  union { float f; unsigned u; } x; x.f = f;
  unsigned r = x.u + 0x7fffu + ((x.u >> 16) & 1u);
  return (short)(r >> 16);
}

// Kt rows 512B / Vt rows 128B: slot ^= row&7 (2-way residue, ~free). Pl padded.
__device__ __forceinline__ int swz(int row) { return (row & 7) << 4; }

// max-reduce across a 16-lane DPP row, pure VALU, bit-exact (R12-proven)
__device__ __forceinline__ float dpp_max16(float v) {
  float t;
  t = __int_as_float(__builtin_amdgcn_mov_dpp(__float_as_int(v), 0xB1, 0xF, 0xF, true));  // quad_perm xor1
  v = fmaxf(v, t);
  t = __int_as_float(__builtin_amdgcn_mov_dpp(__float_as_int(v), 0x4E, 0xF, 0xF, true));  // quad_perm xor2
  v = fmaxf(v, t);
  t = __int_as_float(__builtin_amdgcn_mov_dpp(__float_as_int(v), 0x124, 0xF, 0xF, true)); // row_ror:4
  v = fmaxf(v, t);
  t = __int_as_float(__builtin_amdgcn_mov_dpp(__float_as_int(v), 0x128, 0xF, 0xF, true)); // row_ror:8
  v = fmaxf(v, t);
  return v;
}

// ---------- W fp32 -> bf16, once ----------
__global__ __launch_bounds__(256) void wcvt_kernel(
    const float* __restrict__ W0, const float* __restrict__ W1,
    const float* __restrict__ W2, short* __restrict__ out)
{
  const int m = blockIdx.x >> 5;
  const int i = ((blockIdx.x & 31) * 256 + threadIdx.x) * 8;
  const float* W = (m == 0) ? W0 : ((m == 1) ? W1 : W2);
  floatx4 a = *(const floatx4*)(W + i);
  floatx4 c = *(const floatx4*)(W + i + 4);
  short8 v;
  #pragma unroll
  for (int j = 0; j < 4; ++j) { v[j] = f2bf(a[j]); v[j+4] = f2bf(c[j]); }
  *(short8*)(out + (size_t)m * DIM * DIM + i) = v;
}

// ---------- projection, W-RESIDENT: 64 m-rows/block; C = X.W^T + b ----------
// Wave holds its 32 W-frags (8kk x 4nb) in regs across the whole m-loop.
__global__ __launch_bounds__(256, 2) void proj_kernel(
    const float* __restrict__ X, const short* __restrict__ Wb,
    const float* __restrict__ bias, short* __restrict__ out)
{
  const int lane = threadIdx.x & 63;
  const int wave = threadIdx.x >> 6;
  const int lr = lane & 15, hi = lane >> 4;
  const int m0 = blockIdx.x * 64;
  const int n0 = wave * 64;

  short8 wf[8][4];
  #pragma unroll
  for (int kk = 0; kk < 8; ++kk)
    #pragma unroll
    for (int nb = 0; nb < 4; ++nb)
      wf[kk][nb] = *(const short8*)(Wb + (size_t)(n0 + nb*16 + lr) * DIM + kk*32 + hi*8);

  float bv[4];
  #pragma unroll
  for (int nb = 0; nb < 4; ++nb) bv[nb] = bias[n0 + nb*16 + lr];

  #pragma unroll
  for (int ms = 0; ms < 4; ++ms) {
    const float* xrow = X + (size_t)(m0 + ms*16 + lr) * DIM;
    // batch-issue the 16 X loads for this 16-row chunk (one exposed latency)
    floatx4 xv0[8], xv1[8];
    #pragma unroll
    for (int kk = 0; kk < 8; ++kk) {
      xv0[kk] = *(const floatx4*)(xrow + kk*32 + hi*8);
      xv1[kk] = *(const floatx4*)(xrow + kk*32 + hi*8 + 4);
    }
    f32x4 acc[4] = {(f32x4)0.f,(f32x4)0.f,(f32x4)0.f,(f32x4)0.f};
    #pragma unroll
    for (int kk = 0; kk < 8; ++kk) {
      short8 a;
      #pragma unroll
      for (int j = 0; j < 4; ++j) { a[j] = f2bf(xv0[kk][j]); a[j+4] = f2bf(xv1[kk][j]); }
      #pragma unroll
      for (int nb = 0; nb < 4; ++nb)
        acc[nb] = __builtin_amdgcn_mfma_f32_16x16x32_bf16(a, wf[kk][nb], acc[nb], 0, 0, 0);
    }
    #pragma unroll
    for (int nb = 0; nb < 4; ++nb)
      #pragma unroll
      for (int r = 0; r < 4; ++r)
        out[(size_t)(m0 + ms*16 + hi*4 + r) * DIM + n0 + nb*16 + lr] = f2bf(acc[nb][r] + bv[nb]);
  }
}

// ---------- V projection, W-RESIDENT, output TRANSPOSED: outT[b][d][k] ----------
// 64 rows/block = 2 x 32-row transpose chunks.
__global__ __launch_bounds__(256, 2) void projV_kernel(
    const float* __restrict__ X, const short* __restrict__ Wb,
    const float* __restrict__ bias, short* __restrict__ outT)
{
  __shared__ short tile[32][264];
  const int lane = threadIdx.x & 63;
  const int wave = threadIdx.x >> 6;
  const int lr = lane & 15, hi = lane >> 4;
  const int n0 = wave * 64;

  short8 wf[8][4];
  #pragma unroll
  for (int kk = 0; kk < 8; ++kk)
    #pragma unroll
    for (int nb = 0; nb < 4; ++nb)
      wf[kk][nb] = *(const short8*)(Wb + (size_t)(n0 + nb*16 + lr) * DIM + kk*32 + hi*8);

  float bv[4];
  #pragma unroll
  for (int nb = 0; nb < 4; ++nb) bv[nb] = bias[n0 + nb*16 + lr];

  #pragma unroll
  for (int ms = 0; ms < 2; ++ms) {
    const int mbase = blockIdx.x * 64 + ms * 32;

    f32x4 acc0[4] = {(f32x4)0.f,(f32x4)0.f,(f32x4)0.f,(f32x4)0.f};
    f32x4 acc1[4] = {(f32x4)0.f,(f32x4)0.f,(f32x4)0.f,(f32x4)0.f};
    const float* xr0 = X + (size_t)(mbase + lr) * DIM;
    const float* xr1 = X + (size_t)(mbase + 16 + lr) * DIM;

    #pragma unroll
    for (int kk = 0; kk < 8; ++kk) {
      const int k8 = kk * 32 + hi * 8;
      floatx4 xa = *(const floatx4*)(xr0 + k8);
      floatx4 xb = *(const floatx4*)(xr0 + k8 + 4);
      floatx4 ya = *(const floatx4*)(xr1 + k8);
      floatx4 yb = *(const floatx4*)(xr1 + k8 + 4);
      short8 a0, a1;
      #pragma unroll
      for (int j = 0; j < 4; ++j) {
        a0[j] = f2bf(xa[j]); a0[j+4] = f2bf(xb[j]);
        a1[j] = f2bf(ya[j]); a1[j+4] = f2bf(yb[j]);
      }
      #pragma unroll
      for (int nb = 0; nb < 4; ++nb) {
        acc0[nb] = __builtin_amdgcn_mfma_f32_16x16x32_bf16(a0, wf[kk][nb], acc0[nb], 0, 0, 0);
        acc1[nb] = __builtin_amdgcn_mfma_f32_16x16x32_bf16(a1, wf[kk][nb], acc1[nb], 0, 0, 0);
      }
    }
    #pragma unroll
    for (int nb = 0; nb < 4; ++nb) {
      const int n = n0 + nb*16 + lr;
      #pragma unroll
      for (int r = 0; r < 4; ++r) {
        tile[hi*4 + r][n]      = f2bf(acc0[nb][r] + bv[nb]);
        tile[16 + hi*4 + r][n] = f2bf(acc1[nb][r] + bv[nb]);
      }
    }
    __syncthreads();
    const int t = threadIdx.x;
    short8 v0, v1, v2, v3;
    #pragma unroll
    for (int k = 0; k < 8; ++k) {
      v0[k] = tile[k][t]; v1[k] = tile[k+8][t];
      v2[k] = tile[k+16][t]; v3[k] = tile[k+24][t];
    }
    const int b  = mbase >> 12;
    const int k0 = mbase & (SKL - 1);
    short* p = outT + (size_t)b * DIM * SKL + (size_t)t * SKL + k0;
    *(short8*)(p)      = v0;
    *(short8*)(p + 8)  = v1;
    *(short8*)(p + 16) = v2;
    *(short8*)(p + 24) = v3;
    __syncthreads();   // protect tile before next ms overwrites it
  }
}

// ---------- flash attention: R12 VERBATIM (proven 229 us, absmax 0.05859375) ----------
__global__ __launch_bounds__(512, 1) void attn_kernel(
    const short* __restrict__ Qb, const short* __restrict__ Kb,
    const short* __restrict__ VtG, float* __restrict__ out)
{
  __shared__ alignas(16) short Kt[2][64][256];   // 64 KB, 512B rows, XOR swz
  __shared__ alignas(16) short Vt[2][256][64];   // 64 KB, 128B rows, XOR swz
  __shared__ alignas(16) short Pl[8][16][72];    // 18 KB, 144B rows (padded, no XOR)

  const int tid  = threadIdx.x;
  const int lane = tid & 63;
  const int wave = tid >> 6;                     // 0..7
  const int lr = lane & 15, hi = lane >> 4;

  const int b     = blockIdx.x & 7;     // batch -> XCD pinning (grid=256)
  const int qtile = blockIdx.x >> 3;
  const int q0w   = qtile * 128 + wave * 16;

  const short* Qp = Qb  + ((size_t)b * SQL + q0w) * DIM;
  const short* Kp = Kb  + (size_t)b * SKL * DIM;
  const short* Vp = VtG + (size_t)b * DIM * SKL;

  short8 qf[8];
  #pragma unroll
  for (int kk = 0; kk < 8; ++kk)
    qf[kk] = *(const short8*)(Qp + (size_t)lr * DIM + kk*32 + hi*8);

  f32x4 o[16];
  #pragma unroll
  for (int i = 0; i < 16; ++i) o[i] = (f32x4)0.f;
  float mr[4]   = {-3.0e38f,-3.0e38f,-3.0e38f,-3.0e38f};
  float lacc[4] = {0.f,0.f,0.f,0.f};

  auto stage = [&](int buf, int kv) {
    #pragma unroll
    for (int i = 0; i < 4; ++i) {              // K: 64 rows x 512B
      const int row0 = wave*8 + i*2;
      const int row  = row0 + (lane >> 5);
      const int colb = ((lane & 31) * 16) ^ swz(row);
      gl_lds16((const char*)(Kp + (size_t)(kv + row) * DIM) + colb, (void*)&Kt[buf][row0][0]);
    }
    #pragma unroll
    for (int i = 0; i < 4; ++i) {              // V^T: 256 rows x 128B
      const int d0 = wave*32 + i*8;
      const int d  = d0 + (lane >> 3);
      const int colb = ((lane & 7) * 16) ^ swz(d);
      gl_lds16((const char*)(Vp + (size_t)d * SKL + kv) + colb, (void*)&Vt[buf][d0][0]);
    }
  };

  stage(0, 0);
  __syncthreads();
  int cur = 0;

  const char* plw = (const char*)&Pl[wave][0][0];

  for (int it = 0; it < NIT; ++it) {
    if (it + 1 < NIT) stage(cur ^ 1, (it + 1) * KVB);

    // ---- QK^T: S[16q][64k] ----
    const char* ktb = (const char*)&Kt[cur][0][0];
    f32x4 s[4];
    #pragma unroll
    for (int ks = 0; ks < 4; ++ks) s[ks] = (f32x4)0.f;
    __builtin_amdgcn_s_setprio(1);
    #pragma unroll
    for (int kk = 0; kk < 8; ++kk) {
      #pragma unroll
      for (int ks = 0; ks < 4; ++ks) {
        const int row = ks*16 + lr;
        short8 kf = *(const short8*)(ktb + row*512 + (((kk*64) + hi*16) ^ swz(row)));
        s[ks] = __builtin_amdgcn_mfma_f32_16x16x32_bf16(qf[kk], kf, s[ks], 0, 0, 0);
      }
    }
    __builtin_amdgcn_s_setprio(0);

    // ---- EXACT online softmax (row = hi*4+r, col = ks*16+lr), DPP max-reduce ----
    #pragma unroll
    for (int r = 0; r < 4; ++r) {
      float mx = dpp_max16(fmaxf(fmaxf(s[0][r], s[1][r]), fmaxf(s[2][r], s[3][r])));
      if (mx > mr[r]) {                        // bit-exact skip of sc==1.0 rescale
        const float sc = __expf(mr[r] - mx);   // first iter: exp(-inf)=0
        mr[r] = mx;
        lacc[r] *= sc;
        #pragma unroll
        for (int dt = 0; dt < 16; ++dt) o[dt][r] *= sc;
      }
      const int row = hi*4 + r;
      #pragma unroll
      for (int ks = 0; ks < 4; ++ks) {
        const float p = __expf(s[ks][r] - mr[r]);   // <= 1
        lacc[r] += p;
        *(short*)(plw + row*144 + 2*(ks*16 + lr)) = f2bf(p);
      }
    }

    // ---- PV: O[16q][256d] += P[16q][64k] . V[64k][256d] ----
    const char* vtb = (const char*)&Vt[cur][0][0];
    short8 pa[2];
    #pragma unroll
    for (int kh = 0; kh < 2; ++kh)
      pa[kh] = *(const short8*)(plw + lr*144 + kh*64 + hi*16);
    __builtin_amdgcn_s_setprio(1);
    #pragma unroll
    for (int dt = 0; dt < 16; ++dt) {
      #pragma unroll
      for (int kh = 0; kh < 2; ++kh) {
        const int d = dt*16 + lr;
        short8 vf = *(const short8*)(vtb + d*128 + ((kh*64 + hi*16) ^ swz(d)));
        o[dt] = __builtin_amdgcn_mfma_f32_16x16x32_bf16(pa[kh], vf, o[dt], 0, 0, 0);
      }
    }
    __builtin_amdgcn_s_setprio(0);

    __syncthreads();
    cur ^= 1;
  }

  // ---- epilogue: one cross-lane reduce of l, normalize, store ----
  float lsum[4];
  #pragma unroll
  for (int r = 0; r < 4; ++r) lsum[r] = lacc[r];
  #pragma unroll
  for (int off = 8; off >= 1; off >>= 1)
    #pragma unroll
    for (int r = 0; r < 4; ++r)
      lsum[r] += __shfl_xor(lsum[r], off, 64);

  float* op = out + ((size_t)b * SQL + q0w) * DIM;
  #pragma unroll
  for (int r = 0; r < 4; ++r) {
    const float inv = 1.0f / lsum[r];
    #pragma unroll
    for (int dt = 0; dt < 16; ++dt)
      op[(size_t)(hi*4 + r) * DIM + dt*16 + lr] = o[dt][r] * inv;
  }
}

extern "C" void kernel_launch(void* const* d_in, const int* in_sizes, int n_in,
                              void* d_out, int out_size, void* d_ws, size_t ws_size,
                              hipStream_t stream) {
  const float* query  = (const float*)d_in[0];
  const float* keys   = (const float*)d_in[1];
  const float* values = (const float*)d_in[2];
  const float* Wq = (const float*)d_in[3];
  const float* bq = (const float*)d_in[4];
  const float* Wk = (const float*)d_in[5];
  const float* bk = (const float*)d_in[6];
  const float* Wv = (const float*)d_in[7];
  const float* bv = (const float*)d_in[8];
  float* out = (float*)d_out;

  const size_t elems = (size_t)BATCH * SQL * DIM;
  short* Qb  = (short*)d_ws;
  short* Kb  = Qb + elems;
  short* VtT = Kb + elems;

  const size_t wbytes    = (size_t)3 * DIM * DIM * sizeof(short);
  const size_t need_base = 3 * elems * sizeof(short) + wbytes;
  short* Wb;
  if (ws_size >= need_base) Wb = VtT + elems;
  else Wb = (short*)((char*)d_out + (size_t)out_size * sizeof(float) - wbytes);
  short* Wqb = Wb;
  short* Wkb = Wb + DIM * DIM;
  short* Wvb = Wb + 2 * DIM * DIM;

  dim3 blk(256, 1, 1);
  dim3 blk512(512, 1, 1);
  wcvt_kernel <<<dim3(96, 1, 1),            blk, 0, stream>>>(Wq, Wk, Wv, Wb);
  proj_kernel <<<dim3(BATCH*SQL/64, 1, 1),  blk, 0, stream>>>(query,  Wqb, bq, Qb);
  proj_kernel <<<dim3(BATCH*SKL/64, 1, 1),  blk, 0, stream>>>(keys,   Wkb, bk, Kb);
  projV_kernel<<<dim3(BATCH*SKL/64, 1, 1),  blk, 0, stream>>>(values, Wvb, bv, VtT);
  attn_kernel <<<dim3(BATCH*SQL/128, 1, 1), blk512, 0, stream>>>(Qb, Kb, VtT, out);
}